// Round 1
// baseline (1185.760 us; speedup 1.0000x reference)
//
#include <hip/hip_runtime.h>
#include <math.h>

// Problem constants
#define BATCH 4
#define SEQ   1024
#define DIM_C 1024
#define HEADS 16
#define HDIM  64
#define F3    3072

// ---------------------------------------------------------------------------
// GEMM: out[m,f] = sum_c A[m,c] * W[f,c]   (both K-contiguous, 128x128 tile,
// 8x8 per thread, 256 threads). Variant 1 scatters into q/k/v [b,h,n,d].
// ---------------------------------------------------------------------------
__global__ __launch_bounds__(256) void gemm_qkv_kernel(
    const float* __restrict__ x, const float* __restrict__ w,
    float* __restrict__ qp, float* __restrict__ kp, float* __restrict__ vp)
{
    __shared__ float As[16][132];   // [k][m]
    __shared__ float Bs[16][132];   // [k][f]
    const int t  = threadIdx.x;
    const int tx = t & 15, ty = t >> 4;
    const int m0 = blockIdx.y * 128;
    const int f0 = blockIdx.x * 128;

    float acc[8][8];
    #pragma unroll
    for (int i = 0; i < 8; ++i)
        #pragma unroll
        for (int j = 0; j < 8; ++j) acc[i][j] = 0.f;

    for (int kt = 0; kt < 1024 / 16; ++kt) {
        const int k0 = kt * 16;
        __syncthreads();
        #pragma unroll
        for (int ii = 0; ii < 2; ++ii) {
            int c = t + 256 * ii;
            int row = c >> 2, kc = c & 3;
            float4 ga = *(const float4*)&x[(size_t)(m0 + row) * 1024 + k0 + kc * 4];
            As[kc * 4 + 0][row] = ga.x; As[kc * 4 + 1][row] = ga.y;
            As[kc * 4 + 2][row] = ga.z; As[kc * 4 + 3][row] = ga.w;
            float4 gb = *(const float4*)&w[(size_t)(f0 + row) * 1024 + k0 + kc * 4];
            Bs[kc * 4 + 0][row] = gb.x; Bs[kc * 4 + 1][row] = gb.y;
            Bs[kc * 4 + 2][row] = gb.z; Bs[kc * 4 + 3][row] = gb.w;
        }
        __syncthreads();
        #pragma unroll
        for (int kk = 0; kk < 16; ++kk) {
            float4 a0 = *(float4*)&As[kk][ty * 4];
            float4 a1 = *(float4*)&As[kk][64 + ty * 4];
            float4 b0 = *(float4*)&Bs[kk][tx * 4];
            float4 b1 = *(float4*)&Bs[kk][64 + tx * 4];
            float av[8] = {a0.x, a0.y, a0.z, a0.w, a1.x, a1.y, a1.z, a1.w};
            float bv[8] = {b0.x, b0.y, b0.z, b0.w, b1.x, b1.y, b1.z, b1.w};
            #pragma unroll
            for (int i = 0; i < 8; ++i)
                #pragma unroll
                for (int j = 0; j < 8; ++j) acc[i][j] += av[i] * bv[j];
        }
    }

    // f0 is a multiple of 128 => s = f0>>10 is uniform over the block
    const int s = f0 >> 10;
    float* dst = (s == 0) ? qp : (s == 1) ? kp : vp;
    #pragma unroll
    for (int i = 0; i < 8; ++i) {
        int rloc = (i < 4) ? (ty * 4 + i) : (64 + ty * 4 + (i - 4));
        int m = m0 + rloc;
        int b = m >> 10, n = m & 1023;
        #pragma unroll
        for (int g = 0; g < 2; ++g) {
            int f = f0 + g * 64 + tx * 4;
            int h = (f >> 6) & 15;
            int d = f & 63;   // == tx*4
            float4 o;
            o.x = acc[i][g * 4 + 0]; o.y = acc[i][g * 4 + 1];
            o.z = acc[i][g * 4 + 2]; o.w = acc[i][g * 4 + 3];
            *(float4*)&dst[(((size_t)(b * 16 + h)) * 1024 + n) * 64 + d] = o;
        }
    }
}

__global__ __launch_bounds__(256) void gemm_proj_kernel(
    const float* __restrict__ a, const float* __restrict__ w,
    const float* __restrict__ bias, float* __restrict__ y)
{
    __shared__ float As[16][132];
    __shared__ float Bs[16][132];
    const int t  = threadIdx.x;
    const int tx = t & 15, ty = t >> 4;
    const int m0 = blockIdx.y * 128;
    const int f0 = blockIdx.x * 128;

    float acc[8][8];
    #pragma unroll
    for (int i = 0; i < 8; ++i)
        #pragma unroll
        for (int j = 0; j < 8; ++j) acc[i][j] = 0.f;

    for (int kt = 0; kt < 1024 / 16; ++kt) {
        const int k0 = kt * 16;
        __syncthreads();
        #pragma unroll
        for (int ii = 0; ii < 2; ++ii) {
            int c = t + 256 * ii;
            int row = c >> 2, kc = c & 3;
            float4 ga = *(const float4*)&a[(size_t)(m0 + row) * 1024 + k0 + kc * 4];
            As[kc * 4 + 0][row] = ga.x; As[kc * 4 + 1][row] = ga.y;
            As[kc * 4 + 2][row] = ga.z; As[kc * 4 + 3][row] = ga.w;
            float4 gb = *(const float4*)&w[(size_t)(f0 + row) * 1024 + k0 + kc * 4];
            Bs[kc * 4 + 0][row] = gb.x; Bs[kc * 4 + 1][row] = gb.y;
            Bs[kc * 4 + 2][row] = gb.z; Bs[kc * 4 + 3][row] = gb.w;
        }
        __syncthreads();
        #pragma unroll
        for (int kk = 0; kk < 16; ++kk) {
            float4 a0 = *(float4*)&As[kk][ty * 4];
            float4 a1 = *(float4*)&As[kk][64 + ty * 4];
            float4 b0 = *(float4*)&Bs[kk][tx * 4];
            float4 b1 = *(float4*)&Bs[kk][64 + tx * 4];
            float av[8] = {a0.x, a0.y, a0.z, a0.w, a1.x, a1.y, a1.z, a1.w};
            float bv[8] = {b0.x, b0.y, b0.z, b0.w, b1.x, b1.y, b1.z, b1.w};
            #pragma unroll
            for (int i = 0; i < 8; ++i)
                #pragma unroll
                for (int j = 0; j < 8; ++j) acc[i][j] += av[i] * bv[j];
        }
    }

    #pragma unroll
    for (int i = 0; i < 8; ++i) {
        int rloc = (i < 4) ? (ty * 4 + i) : (64 + ty * 4 + (i - 4));
        int m = m0 + rloc;
        #pragma unroll
        for (int g = 0; g < 2; ++g) {
            int f = f0 + g * 64 + tx * 4;
            float4 b4 = *(const float4*)&bias[f];
            float4 o;
            o.x = acc[i][g * 4 + 0] + b4.x; o.y = acc[i][g * 4 + 1] + b4.y;
            o.z = acc[i][g * 4 + 2] + b4.z; o.w = acc[i][g * 4 + 3] + b4.w;
            *(float4*)&y[(size_t)m * 1024 + f] = o;
        }
    }
}

// ---------------------------------------------------------------------------
// Flash-style causal attention with relative skew.
// score[n,m] = (q[n]·k[m] + q[n]·Er[1023-(n-m)]) * 0.125  for m<=n.
// Block: 16 Q-rows (one (b,h,n-tile)), 256 threads = 16 rows x 16 lanes,
// each lane owns 4 output dims and 4 score columns per KV tile of 64.
// ---------------------------------------------------------------------------
__global__ __launch_bounds__(256) void attn_kernel(
    const float* __restrict__ q, const float* __restrict__ k,
    const float* __restrict__ v, const float* __restrict__ Er,
    float* __restrict__ out)
{
    __shared__ float k_s[64][68];
    __shared__ float v_s[64][68];
    __shared__ float e_s[80][68];
    __shared__ float p_s[16][68];

    const int t  = threadIdx.x;
    const int lc = t & 15, r = t >> 4;
    const int b  = blockIdx.z, h = blockIdx.y;
    const int n0 = blockIdx.x * 16;
    const int n  = n0 + r;

    const float* qb = q + (size_t)(b * 16 + h) * 1024 * 64;
    const float* kb = k + (size_t)(b * 16 + h) * 1024 * 64;
    const float* vb = v + (size_t)(b * 16 + h) * 1024 * 64;

    // hoist this thread's q row into registers (16 float4 = 64 VGPRs)
    float4 qreg[16];
    #pragma unroll
    for (int d4 = 0; d4 < 16; ++d4)
        qreg[d4] = *(const float4*)&qb[(size_t)n * 64 + d4 * 4];

    float mrow = -1e30f, lrow = 0.f;
    float4 O = {0.f, 0.f, 0.f, 0.f};

    const int ntiles = (n0 + 79) >> 6;   // causal: tiles with m0 <= n0+15
    for (int tt = 0; tt < ntiles; ++tt) {
        const int m0 = tt * 64;
        const int eBase = 1024 - 16 - n0 + m0;   // Er row of (r=15, mloc=0)
        __syncthreads();   // prev iter's reads done before restage
        #pragma unroll
        for (int ii = 0; ii < 4; ++ii) {
            int c = t + 256 * ii;
            int row = c >> 4, dc = c & 15;
            *(float4*)&k_s[row][dc * 4] = *(const float4*)&kb[(size_t)(m0 + row) * 64 + dc * 4];
            *(float4*)&v_s[row][dc * 4] = *(const float4*)&vb[(size_t)(m0 + row) * 64 + dc * 4];
        }
        #pragma unroll
        for (int ii = 0; ii < 5; ++ii) {
            int c = t + 256 * ii;
            int row = c >> 4, dc = c & 15;
            int g = eBase + row;
            g = (g < 0) ? 0 : ((g > 1023) ? 1023 : g);   // clamped rows feed masked entries only
            *(float4*)&e_s[row][dc * 4] = *(const float4*)&Er[(size_t)g * 64 + dc * 4];
        }
        __syncthreads();

        // scores: 4 columns per lane, mloc = lc + 16*jj (stride-16 => 2-way LDS)
        float sv[4];
        #pragma unroll
        for (int jj = 0; jj < 4; ++jj) {
            const int mloc = lc + 16 * jj;
            const int mg   = m0 + mloc;
            const int erow = 15 - r + mloc;   // in [0,78]
            float ca = 0.f, ra = 0.f;
            #pragma unroll
            for (int d4 = 0; d4 < 16; ++d4) {
                float4 qv = qreg[d4];
                float4 kv = *(float4*)&k_s[mloc][d4 * 4];
                float4 ev = *(float4*)&e_s[erow][d4 * 4];
                ca += qv.x * kv.x + qv.y * kv.y + qv.z * kv.z + qv.w * kv.w;
                ra += qv.x * ev.x + qv.y * ev.y + qv.z * ev.z + qv.w * ev.w;
            }
            sv[jj] = (mg <= n) ? (ca + ra) * 0.125f : -1e30f;
        }

        // online softmax over this tile (row = 16 consecutive lanes)
        float tmax = fmaxf(fmaxf(sv[0], sv[1]), fmaxf(sv[2], sv[3]));
        #pragma unroll
        for (int off = 1; off < 16; off <<= 1)
            tmax = fmaxf(tmax, __shfl_xor(tmax, off, 16));
        float mnew = fmaxf(mrow, tmax);
        float psum = 0.f;
        #pragma unroll
        for (int jj = 0; jj < 4; ++jj) {
            float p = __expf(sv[jj] - mnew);
            p_s[r][lc + 16 * jj] = p;
            psum += p;
        }
        #pragma unroll
        for (int off = 1; off < 16; off <<= 1)
            psum += __shfl_xor(psum, off, 16);
        float alpha = __expf(mrow - mnew);
        lrow = lrow * alpha + psum;
        O.x *= alpha; O.y *= alpha; O.z *= alpha; O.w *= alpha;
        mrow = mnew;
        __syncthreads();   // p_s visible to all lanes of the row

        // PV: this lane's 4 output dims, c = lc*4..lc*4+3
        #pragma unroll
        for (int mloc = 0; mloc < 64; ++mloc) {
            float p = p_s[r][mloc];
            float4 vv = *(float4*)&v_s[mloc][lc * 4];
            O.x += p * vv.x; O.y += p * vv.y; O.z += p * vv.z; O.w += p * vv.w;
        }
    }

    float inv = 1.f / lrow;
    float4 res;
    res.x = O.x * inv; res.y = O.y * inv; res.z = O.z * inv; res.w = O.w * inv;
    // attn output laid [b][n][h*64+d] so the proj GEMM reads it as (4096,1024)
    *(float4*)&out[((size_t)(b * 1024) + n) * 1024 + h * 64 + lc * 4] = res;
}

// ---------------------------------------------------------------------------
extern "C" void kernel_launch(void* const* d_in, const int* in_sizes, int n_in,
                              void* d_out, int out_size, void* d_ws, size_t ws_size,
                              hipStream_t stream)
{
    const float* x     = (const float*)d_in[0];
    const float* Wqkv  = (const float*)d_in[1];
    const float* Wproj = (const float*)d_in[2];
    const float* bproj = (const float*)d_in[3];
    const float* Er    = (const float*)d_in[4];
    float* out = (float*)d_out;

    float* ws = (float*)d_ws;
    const size_t per = (size_t)BATCH * HEADS * SEQ * HDIM;   // 4,194,304 floats
    float* qw   = ws;
    float* kw   = ws + per;
    float* vw   = ws + 2 * per;
    float* attn = ws + 3 * per;

    // qkv GEMM: (4096 x 3072 x 1024), scatter to [b,h,n,d]
    gemm_qkv_kernel<<<dim3(F3 / 128, (BATCH * SEQ) / 128), 256, 0, stream>>>(
        x, Wqkv, qw, kw, vw);

    // attention: grid (n-tiles, heads, batch)
    attn_kernel<<<dim3(SEQ / 16, HEADS, BATCH), 256, 0, stream>>>(
        qw, kw, vw, Er, attn);

    // proj GEMM + bias: (4096 x 1024 x 1024)
    gemm_proj_kernel<<<dim3(DIM_C / 128, (BATCH * SEQ) / 128), 256, 0, stream>>>(
        attn, Wproj, bproj, out);
}

// Round 2
// 619.131 us; speedup vs baseline: 1.9152x; 1.9152x over previous
//
#include <hip/hip_runtime.h>
#include <math.h>

#define BATCH 4
#define SEQ   1024
#define DIM_C 1024
#define HEADS 16
#define HDIM  64
#define F3    3072

typedef short bf8 __attribute__((ext_vector_type(8)));
typedef float f32x4 __attribute__((ext_vector_type(4)));

__device__ __forceinline__ ushort f2bf(float f) {
    union { float f; unsigned u; } c; c.f = f;
    unsigned u = c.u + 0x7fffu + ((c.u >> 16) & 1u);
    return (ushort)(u >> 16);
}
__device__ __forceinline__ float bf2f(ushort s) {
    union { unsigned u; float f; } c; c.u = ((unsigned)s) << 16;
    return c.f;
}

// ---------------------------------------------------------------------------
// qkv GEMM: out[m,f] = sum_c x[m,c] * W[f,c]. q,k written bf16 [b,h,n,d];
// v written fp32 [b,h,n,d].
// ---------------------------------------------------------------------------
__global__ __launch_bounds__(256) void gemm_qkv_kernel(
    const float* __restrict__ x, const float* __restrict__ w,
    ushort* __restrict__ qp, ushort* __restrict__ kp, float* __restrict__ vp)
{
    __shared__ float As[16][132];
    __shared__ float Bs[16][132];
    const int t  = threadIdx.x;
    const int tx = t & 15, ty = t >> 4;
    const int m0 = blockIdx.y * 128;
    const int f0 = blockIdx.x * 128;

    float acc[8][8];
    #pragma unroll
    for (int i = 0; i < 8; ++i)
        #pragma unroll
        for (int j = 0; j < 8; ++j) acc[i][j] = 0.f;

    for (int kt = 0; kt < 1024 / 16; ++kt) {
        const int k0 = kt * 16;
        __syncthreads();
        #pragma unroll
        for (int ii = 0; ii < 2; ++ii) {
            int c = t + 256 * ii;
            int row = c >> 2, kc = c & 3;
            float4 ga = *(const float4*)&x[(size_t)(m0 + row) * 1024 + k0 + kc * 4];
            As[kc * 4 + 0][row] = ga.x; As[kc * 4 + 1][row] = ga.y;
            As[kc * 4 + 2][row] = ga.z; As[kc * 4 + 3][row] = ga.w;
            float4 gb = *(const float4*)&w[(size_t)(f0 + row) * 1024 + k0 + kc * 4];
            Bs[kc * 4 + 0][row] = gb.x; Bs[kc * 4 + 1][row] = gb.y;
            Bs[kc * 4 + 2][row] = gb.z; Bs[kc * 4 + 3][row] = gb.w;
        }
        __syncthreads();
        #pragma unroll
        for (int kk = 0; kk < 16; ++kk) {
            float4 a0 = *(float4*)&As[kk][ty * 4];
            float4 a1 = *(float4*)&As[kk][64 + ty * 4];
            float4 b0 = *(float4*)&Bs[kk][tx * 4];
            float4 b1 = *(float4*)&Bs[kk][64 + tx * 4];
            float av[8] = {a0.x, a0.y, a0.z, a0.w, a1.x, a1.y, a1.z, a1.w};
            float bv[8] = {b0.x, b0.y, b0.z, b0.w, b1.x, b1.y, b1.z, b1.w};
            #pragma unroll
            for (int i = 0; i < 8; ++i)
                #pragma unroll
                for (int j = 0; j < 8; ++j) acc[i][j] += av[i] * bv[j];
        }
    }

    const int s = f0 >> 10;   // uniform: 0=q 1=k 2=v
    #pragma unroll
    for (int i = 0; i < 8; ++i) {
        int rloc = (i < 4) ? (ty * 4 + i) : (64 + ty * 4 + (i - 4));
        int m = m0 + rloc;
        int b = m >> 10, n = m & 1023;
        #pragma unroll
        for (int g = 0; g < 2; ++g) {
            int f = f0 + g * 64 + tx * 4;
            int h = (f >> 6) & 15;
            int d = f & 63;   // == tx*4
            size_t idx = (((size_t)(b * 16 + h)) * 1024 + n) * 64 + d;
            if (s < 2) {
                ushort* dst = (s == 0) ? qp : kp;
                ushort4 o;
                o.x = f2bf(acc[i][g * 4 + 0]); o.y = f2bf(acc[i][g * 4 + 1]);
                o.z = f2bf(acc[i][g * 4 + 2]); o.w = f2bf(acc[i][g * 4 + 3]);
                *(ushort4*)&dst[idx] = o;
            } else {
                float4 o;
                o.x = acc[i][g * 4 + 0]; o.y = acc[i][g * 4 + 1];
                o.z = acc[i][g * 4 + 2]; o.w = acc[i][g * 4 + 3];
                *(float4*)&vp[idx] = o;
            }
        }
    }
}

__global__ __launch_bounds__(256) void gemm_proj_kernel(
    const float* __restrict__ a, const float* __restrict__ w,
    const float* __restrict__ bias, float* __restrict__ y)
{
    __shared__ float As[16][132];
    __shared__ float Bs[16][132];
    const int t  = threadIdx.x;
    const int tx = t & 15, ty = t >> 4;
    const int m0 = blockIdx.y * 128;
    const int f0 = blockIdx.x * 128;

    float acc[8][8];
    #pragma unroll
    for (int i = 0; i < 8; ++i)
        #pragma unroll
        for (int j = 0; j < 8; ++j) acc[i][j] = 0.f;

    for (int kt = 0; kt < 1024 / 16; ++kt) {
        const int k0 = kt * 16;
        __syncthreads();
        #pragma unroll
        for (int ii = 0; ii < 2; ++ii) {
            int c = t + 256 * ii;
            int row = c >> 2, kc = c & 3;
            float4 ga = *(const float4*)&a[(size_t)(m0 + row) * 1024 + k0 + kc * 4];
            As[kc * 4 + 0][row] = ga.x; As[kc * 4 + 1][row] = ga.y;
            As[kc * 4 + 2][row] = ga.z; As[kc * 4 + 3][row] = ga.w;
            float4 gb = *(const float4*)&w[(size_t)(f0 + row) * 1024 + k0 + kc * 4];
            Bs[kc * 4 + 0][row] = gb.x; Bs[kc * 4 + 1][row] = gb.y;
            Bs[kc * 4 + 2][row] = gb.z; Bs[kc * 4 + 3][row] = gb.w;
        }
        __syncthreads();
        #pragma unroll
        for (int kk = 0; kk < 16; ++kk) {
            float4 a0 = *(float4*)&As[kk][ty * 4];
            float4 a1 = *(float4*)&As[kk][64 + ty * 4];
            float4 b0 = *(float4*)&Bs[kk][tx * 4];
            float4 b1 = *(float4*)&Bs[kk][64 + tx * 4];
            float av[8] = {a0.x, a0.y, a0.z, a0.w, a1.x, a1.y, a1.z, a1.w};
            float bv[8] = {b0.x, b0.y, b0.z, b0.w, b1.x, b1.y, b1.z, b1.w};
            #pragma unroll
            for (int i = 0; i < 8; ++i)
                #pragma unroll
                for (int j = 0; j < 8; ++j) acc[i][j] += av[i] * bv[j];
        }
    }

    #pragma unroll
    for (int i = 0; i < 8; ++i) {
        int rloc = (i < 4) ? (ty * 4 + i) : (64 + ty * 4 + (i - 4));
        int m = m0 + rloc;
        #pragma unroll
        for (int g = 0; g < 2; ++g) {
            int f = f0 + g * 64 + tx * 4;
            float4 b4 = *(const float4*)&bias[f];
            float4 o;
            o.x = acc[i][g * 4 + 0] + b4.x; o.y = acc[i][g * 4 + 1] + b4.y;
            o.z = acc[i][g * 4 + 2] + b4.z; o.w = acc[i][g * 4 + 3] + b4.w;
            *(float4*)&y[(size_t)m * 1024 + f] = o;
        }
    }
}

// ---------------------------------------------------------------------------
// Er fp32 -> bf16 converter (1024 x 64)
// ---------------------------------------------------------------------------
__global__ void er_convert_kernel(const float* __restrict__ er, ushort* __restrict__ erb)
{
    int i = (blockIdx.x * 256 + threadIdx.x) * 4;
    float4 v = *(const float4*)&er[i];
    ushort4 o;
    o.x = f2bf(v.x); o.y = f2bf(v.y); o.z = f2bf(v.z); o.w = f2bf(v.w);
    *(ushort4*)&erb[i] = o;
}

// ---------------------------------------------------------------------------
// MFMA flash attention with relative skew (bf16 inputs, fp32 accumulate).
// Block = 64 Q-rows of one (b,h); 4 waves x 16 rows. KV tiles of 64.
// score[n,m] = (q[n].k[m] + q[n].Er[1023-n+m]) * 0.125, m<=n.
// rel computed as 16x80 MFMA tile R = q . Er_tile^T, gathered at
// colR = (m-m0) + 15 - row via LDS round-trip.
// ---------------------------------------------------------------------------
__global__ __launch_bounds__(256) void attn_mfma_kernel(
    const ushort* __restrict__ qg, const ushort* __restrict__ kg,
    const float* __restrict__ vg, const ushort* __restrict__ erg,
    float* __restrict__ outp)
{
    __shared__ __align__(16) ushort k_s[64][72];
    __shared__ __align__(16) ushort e_s[128][72];
    __shared__ __align__(16) ushort vt_s[64][72];
    __shared__ __align__(16) ushort r_s[4][16][84];
    __shared__ __align__(16) ushort p_s[4][16][72];

    const int t   = threadIdx.x;
    const int w   = t >> 6;
    const int lane = t & 63;
    const int lc  = lane & 15, g4 = lane >> 4;
    const int b   = blockIdx.z, h = blockIdx.y, bx = blockIdx.x;
    const int n0  = bx * 64;
    const int n0w = n0 + w * 16;

    const ushort* qb = qg + ((size_t)(b * 16 + h)) * 1024 * 64;
    const ushort* kb = kg + ((size_t)(b * 16 + h)) * 1024 * 64;
    const float*  vb = vg + ((size_t)(b * 16 + h)) * 1024 * 64;

    // q A-fragments: A[m=lc][k = c*32 + g4*8 + j]
    bf8 qf[2];
    #pragma unroll
    for (int c = 0; c < 2; ++c)
        qf[c] = *(const bf8*)&qb[(size_t)(n0w + lc) * 64 + c * 32 + g4 * 8];

    const f32x4 z4 = {0.f, 0.f, 0.f, 0.f};
    f32x4 od[4] = {z4, z4, z4, z4};
    float mrow[4] = {-1e30f, -1e30f, -1e30f, -1e30f};
    float lrow[4] = {0.f, 0.f, 0.f, 0.f};

    const int ntiles = bx + 1;
    for (int tt = 0; tt < ntiles; ++tt) {
        const int m0 = tt * 64;
        const int eB = 960 - n0 + m0;   // >= 0 always
        __syncthreads();
        // stage K tile (bf16 global -> LDS), rows [m0, m0+64)
        #pragma unroll
        for (int ii = 0; ii < 2; ++ii) {
            int c = t + 256 * ii;          // 512 chunks of 8 elems
            int row = c >> 3, d8 = c & 7;
            *(uint4*)&k_s[row][d8 * 8] = *(const uint4*)&kb[(size_t)(m0 + row) * 64 + d8 * 8];
        }
        // stage Er tile: rows [eB, eB+128), clamped high (clamped rows are masked)
        #pragma unroll
        for (int ii = 0; ii < 4; ++ii) {
            int c = t + 256 * ii;          // 1024 chunks
            int row = c >> 3, d8 = c & 7;
            int g = eB + row; g = (g > 1023) ? 1023 : g;
            *(uint4*)&e_s[row][d8 * 8] = *(const uint4*)&erg[(size_t)g * 64 + d8 * 8];
        }
        // stage V transposed (fp32 -> bf16): vt_s[d][m]
        #pragma unroll
        for (int ii = 0; ii < 4; ++ii) {
            int c = t + 256 * ii;          // 1024 chunks of 4 elems
            int m = c >> 4, d4 = c & 15;
            float4 vv = *(const float4*)&vb[(size_t)(m0 + m) * 64 + d4 * 4];
            vt_s[d4 * 4 + 0][m] = f2bf(vv.x);
            vt_s[d4 * 4 + 1][m] = f2bf(vv.y);
            vt_s[d4 * 4 + 2][m] = f2bf(vv.z);
            vt_s[d4 * 4 + 3][m] = f2bf(vv.w);
        }
        __syncthreads();

        if (m0 <= n0w + 15) {   // wave-uniform: skip fully-masked tiles
            // content scores: S[16][64] in 4 col-quads
            f32x4 sc[4] = {z4, z4, z4, z4};
            #pragma unroll
            for (int jt = 0; jt < 4; ++jt)
                #pragma unroll
                for (int c = 0; c < 2; ++c)
                    sc[jt] = __builtin_amdgcn_mfma_f32_16x16x32_bf16(
                        qf[c], *(const bf8*)&k_s[jt * 16 + lc][c * 32 + g4 * 8], sc[jt], 0, 0, 0);

            // rel tile: R[16][80]
            f32x4 rc[5] = {z4, z4, z4, z4, z4};
            const int ew0 = 48 - 16 * w;
            #pragma unroll
            for (int jr = 0; jr < 5; ++jr)
                #pragma unroll
                for (int c = 0; c < 2; ++c)
                    rc[jr] = __builtin_amdgcn_mfma_f32_16x16x32_bf16(
                        qf[c], *(const bf8*)&e_s[ew0 + jr * 16 + lc][c * 32 + g4 * 8], rc[jr], 0, 0, 0);

            // write R to LDS (C-layout: row=g4*4+i, colR=jr*16+lc)
            #pragma unroll
            for (int jr = 0; jr < 5; ++jr)
                #pragma unroll
                for (int i = 0; i < 4; ++i)
                    r_s[w][g4 * 4 + i][jr * 16 + lc] = f2bf(rc[jr][i]);
            asm volatile("s_waitcnt lgkmcnt(0)" ::: "memory");

            // assemble scores + online softmax (per row-reg i)
            float a_[4];
            #pragma unroll
            for (int i = 0; i < 4; ++i) {
                const int row = g4 * 4 + i;
                const int n   = n0w + row;
                float sv[4];
                #pragma unroll
                for (int jt = 0; jt < 4; ++jt) {
                    int colR = jt * 16 + lc + 15 - row;     // in [0,78]
                    float rel = bf2f(r_s[w][row][colR]);
                    float s = (sc[jt][i] + rel) * 0.125f;
                    int m = m0 + jt * 16 + lc;
                    sv[jt] = (m <= n) ? s : -1e30f;
                }
                float tmax = fmaxf(fmaxf(sv[0], sv[1]), fmaxf(sv[2], sv[3]));
                #pragma unroll
                for (int off = 1; off < 16; off <<= 1)
                    tmax = fmaxf(tmax, __shfl_xor(tmax, off, 16));
                float mnew = fmaxf(mrow[i], tmax);
                float psum = 0.f;
                #pragma unroll
                for (int jt = 0; jt < 4; ++jt) {
                    float p = __expf(sv[jt] - mnew);
                    p_s[w][row][jt * 16 + lc] = f2bf(p);
                    psum += p;
                }
                #pragma unroll
                for (int off = 1; off < 16; off <<= 1)
                    psum += __shfl_xor(psum, off, 16);
                float alpha = __expf(mrow[i] - mnew);
                mrow[i] = mnew;
                lrow[i] = lrow[i] * alpha + psum;
                a_[i] = alpha;
            }

            // rescale O
            #pragma unroll
            for (int dt = 0; dt < 4; ++dt)
                #pragma unroll
                for (int i = 0; i < 4; ++i)
                    od[dt][i] *= a_[i];

            asm volatile("s_waitcnt lgkmcnt(0)" ::: "memory");
            // PV: A = P (A-layout from p_s), B = V^T
            bf8 pf[2];
            #pragma unroll
            for (int c = 0; c < 2; ++c)
                pf[c] = *(const bf8*)&p_s[w][lc][c * 32 + g4 * 8];
            #pragma unroll
            for (int dt = 0; dt < 4; ++dt)
                #pragma unroll
                for (int c = 0; c < 2; ++c)
                    od[dt] = __builtin_amdgcn_mfma_f32_16x16x32_bf16(
                        pf[c], *(const bf8*)&vt_s[dt * 16 + lc][c * 32 + g4 * 8], od[dt], 0, 0, 0);
        }
    }

    // epilogue: out[b][n][h*64+d] fp32
    #pragma unroll
    for (int i = 0; i < 4; ++i) {
        const int row = g4 * 4 + i;
        const int n   = n0w + row;
        const float inv = 1.f / lrow[i];
        #pragma unroll
        for (int dt = 0; dt < 4; ++dt)
            outp[((size_t)(b * 1024) + n) * 1024 + h * 64 + dt * 16 + lc] = od[dt][i] * inv;
    }
}

// ---------------------------------------------------------------------------
extern "C" void kernel_launch(void* const* d_in, const int* in_sizes, int n_in,
                              void* d_out, int out_size, void* d_ws, size_t ws_size,
                              hipStream_t stream)
{
    const float* x     = (const float*)d_in[0];
    const float* Wqkv  = (const float*)d_in[1];
    const float* Wproj = (const float*)d_in[2];
    const float* bproj = (const float*)d_in[3];
    const float* Er    = (const float*)d_in[4];
    float* out = (float*)d_out;

    char* ws = (char*)d_ws;
    const size_t per = (size_t)BATCH * HEADS * SEQ * HDIM;   // 4,194,304 elems
    ushort* qw   = (ushort*)(ws);
    ushort* kw   = (ushort*)(ws + per * 2);
    float*  vw   = (float*) (ws + per * 4);
    float*  attn = (float*) (ws + per * 4 + per * 4);
    ushort* erb  = (ushort*)(ws + per * 4 + per * 8);

    er_convert_kernel<<<dim3(64), 256, 0, stream>>>(Er, erb);

    gemm_qkv_kernel<<<dim3(F3 / 128, (BATCH * SEQ) / 128), 256, 0, stream>>>(
        x, Wqkv, qw, kw, vw);

    attn_mfma_kernel<<<dim3(SEQ / 64, HEADS, BATCH), 256, 0, stream>>>(
        qw, kw, vw, erb, attn);

    gemm_proj_kernel<<<dim3(DIM_C / 128, (BATCH * SEQ) / 128), 256, 0, stream>>>(
        attn, Wproj, bproj, out);
}

// Round 3
// 269.616 us; speedup vs baseline: 4.3980x; 2.2963x over previous
//
#include <hip/hip_runtime.h>
#include <math.h>

#define BATCH 4
#define SEQ   1024
#define DIM_C 1024
#define HEADS 16
#define HDIM  64
#define F3    3072

typedef short bf8 __attribute__((ext_vector_type(8)));
typedef float f32x4 __attribute__((ext_vector_type(4)));

__device__ __forceinline__ ushort f2bf(float f) {
    union { float f; unsigned u; } c; c.f = f;
    unsigned u = c.u + 0x7fffu + ((c.u >> 16) & 1u);
    return (ushort)(u >> 16);
}
__device__ __forceinline__ float bf2f(ushort s) {
    union { unsigned u; float f; } c; c.u = ((unsigned)s) << 16;
    return c.f;
}

// async 16B global -> LDS (wave-uniform LDS base + lane*16)
__device__ __forceinline__ void load_lds16(const ushort* g, ushort* l) {
    __builtin_amdgcn_global_load_lds(
        (const __attribute__((address_space(1))) unsigned int*)g,
        (__attribute__((address_space(3))) unsigned int*)l, 16, 0, 0);
}

// ---------------------------------------------------------------------------
// fp32 -> bf16 bulk convert, 8 elems/thread. n must be divisible by 2048.
// ---------------------------------------------------------------------------
__global__ __launch_bounds__(256) void cvt_kernel(
    const float* __restrict__ in, ushort* __restrict__ out)
{
    size_t i = ((size_t)blockIdx.x * 256 + threadIdx.x) * 8;
    float4 v0 = *(const float4*)&in[i];
    float4 v1 = *(const float4*)&in[i + 4];
    ushort o[8];
    o[0] = f2bf(v0.x); o[1] = f2bf(v0.y); o[2] = f2bf(v0.z); o[3] = f2bf(v0.w);
    o[4] = f2bf(v1.x); o[5] = f2bf(v1.y); o[6] = f2bf(v1.z); o[7] = f2bf(v1.w);
    *(uint4*)&out[i] = *(uint4*)o;
}

// ---------------------------------------------------------------------------
// m97-style MFMA GEMM core: C[m,f] = sum_c A[m,c]*B[f,c], A MxK, B NxK bf16
// row-major (K-contiguous), K=1024. 128x128 tile, BK=32, 4 waves (2x2 of
// 64x64), 16 MFMA/wave/K-step, async global->LDS staging.
// acc[mb][nb][i] = C[m0 + wm + mb*16 + g4*4 + i][f0 + wn + nb*16 + lc]
// ---------------------------------------------------------------------------
__device__ __forceinline__ void gemm_core(
    const ushort* __restrict__ a, const ushort* __restrict__ b,
    ushort* As, ushort* Bs, int m0, int f0, int t, f32x4 (&acc)[4][4])
{
    const int lane = t & 63, w = t >> 6;
    const int lc = lane & 15, g4 = lane >> 4;
    const int wm = (w >> 1) * 64, wn = (w & 1) * 64;
    const int rowS = w * 32 + (lane >> 2);      // staging row (ii adds 16)
    const int kkS  = (lane & 3) * 8;            // staging k offset

    for (int kt = 0; kt < 32; ++kt) {
        const int k0 = kt * 32;
        __syncthreads();
        #pragma unroll
        for (int ii = 0; ii < 2; ++ii) {
            load_lds16(&a[(size_t)(m0 + rowS + ii * 16) * 1024 + k0 + kkS],
                       &As[(w * 2 + ii) * 512]);
            load_lds16(&b[(size_t)(f0 + rowS + ii * 16) * 1024 + k0 + kkS],
                       &Bs[(w * 2 + ii) * 512]);
        }
        __syncthreads();
        bf8 af[4], bfr[4];
        #pragma unroll
        for (int mb = 0; mb < 4; ++mb)
            af[mb] = *(const bf8*)&As[(wm + mb * 16 + lc) * 32 + g4 * 8];
        #pragma unroll
        for (int nb = 0; nb < 4; ++nb)
            bfr[nb] = *(const bf8*)&Bs[(wn + nb * 16 + lc) * 32 + g4 * 8];
        #pragma unroll
        for (int mb = 0; mb < 4; ++mb)
            #pragma unroll
            for (int nb = 0; nb < 4; ++nb)
                acc[mb][nb] = __builtin_amdgcn_mfma_f32_16x16x32_bf16(
                    af[mb], bfr[nb], acc[mb][nb], 0, 0, 0);
    }
}

// qkv: A = x_bf16 (4096x1024), B = Wqkv_bf16 (3072x1024), scatter bf16 q/k/v
__global__ __launch_bounds__(256) void gemm_qkv_mfma(
    const ushort* __restrict__ xb, const ushort* __restrict__ wb,
    ushort* __restrict__ qp, ushort* __restrict__ kp, ushort* __restrict__ vp)
{
    __shared__ __align__(16) ushort As[128 * 32];
    __shared__ __align__(16) ushort Bs[128 * 32];
    const int t = threadIdx.x;
    const int m0 = blockIdx.y * 128, f0 = blockIdx.x * 128;
    f32x4 acc[4][4];
    #pragma unroll
    for (int mb = 0; mb < 4; ++mb)
        #pragma unroll
        for (int nb = 0; nb < 4; ++nb) acc[mb][nb] = (f32x4){0.f, 0.f, 0.f, 0.f};

    gemm_core(xb, wb, As, Bs, m0, f0, t, acc);

    const int lane = t & 63, w = t >> 6;
    const int lc = lane & 15, g4 = lane >> 4;
    const int wm = (w >> 1) * 64, wn = (w & 1) * 64;
    const int s = f0 >> 10;                      // uniform: 0=q 1=k 2=v
    ushort* dst = (s == 0) ? qp : (s == 1) ? kp : vp;
    #pragma unroll
    for (int mb = 0; mb < 4; ++mb)
        #pragma unroll
        for (int nb = 0; nb < 4; ++nb) {
            const int f = f0 + wn + nb * 16 + lc;
            const int h = (f >> 6) & 15, d = f & 63;
            #pragma unroll
            for (int i = 0; i < 4; ++i) {
                const int m = m0 + wm + mb * 16 + g4 * 4 + i;
                const int b = m >> 10, n = m & 1023;
                dst[(((size_t)(b * 16 + h)) * 1024 + n) * 64 + d] = f2bf(acc[mb][nb][i]);
            }
        }
}

// proj: A = attn_bf16 (4096x1024), B = Wproj_bf16 (1024x1024), +bias, fp32 out
__global__ __launch_bounds__(256) void gemm_proj_mfma(
    const ushort* __restrict__ ab, const ushort* __restrict__ wb,
    const float* __restrict__ bias, float* __restrict__ y)
{
    __shared__ __align__(16) ushort As[128 * 32];
    __shared__ __align__(16) ushort Bs[128 * 32];
    const int t = threadIdx.x;
    const int m0 = blockIdx.y * 128, f0 = blockIdx.x * 128;
    f32x4 acc[4][4];
    #pragma unroll
    for (int mb = 0; mb < 4; ++mb)
        #pragma unroll
        for (int nb = 0; nb < 4; ++nb) acc[mb][nb] = (f32x4){0.f, 0.f, 0.f, 0.f};

    gemm_core(ab, wb, As, Bs, m0, f0, t, acc);

    const int lane = t & 63, w = t >> 6;
    const int lc = lane & 15, g4 = lane >> 4;
    const int wm = (w >> 1) * 64, wn = (w & 1) * 64;
    #pragma unroll
    for (int mb = 0; mb < 4; ++mb)
        #pragma unroll
        for (int nb = 0; nb < 4; ++nb) {
            const int f = f0 + wn + nb * 16 + lc;
            const float bv = bias[f];
            #pragma unroll
            for (int i = 0; i < 4; ++i) {
                const int m = m0 + wm + mb * 16 + g4 * 4 + i;
                y[(size_t)m * 1024 + f] = acc[mb][nb][i] + bv;
            }
        }
}

// ---------------------------------------------------------------------------
// MFMA flash attention with relative skew (all-bf16 inputs, fp32 accumulate).
// Block = 64 Q-rows of one (b,h); 4 waves x 16 rows. KV tiles of 64.
// score[n,m] = (q[n].k[m] + q[n].Er[1023-n+m]) * 0.125, m<=n.
// ---------------------------------------------------------------------------
__global__ __launch_bounds__(256) void attn_mfma_kernel(
    const ushort* __restrict__ qg, const ushort* __restrict__ kg,
    const ushort* __restrict__ vg, const ushort* __restrict__ erg,
    ushort* __restrict__ outp)
{
    __shared__ __align__(16) ushort k_s[64][72];
    __shared__ __align__(16) ushort e_s[128][72];
    __shared__ __align__(16) ushort vt_s[64][72];
    __shared__ __align__(16) ushort r_s[4][16][84];
    __shared__ __align__(16) ushort p_s[4][16][72];

    const int t   = threadIdx.x;
    const int w   = t >> 6;
    const int lane = t & 63;
    const int lc  = lane & 15, g4 = lane >> 4;
    const int b   = blockIdx.z, h = blockIdx.y, bx = blockIdx.x;
    const int n0  = bx * 64;
    const int n0w = n0 + w * 16;

    const ushort* qb = qg + ((size_t)(b * 16 + h)) * 1024 * 64;
    const ushort* kb = kg + ((size_t)(b * 16 + h)) * 1024 * 64;
    const ushort* vb = vg + ((size_t)(b * 16 + h)) * 1024 * 64;

    bf8 qf[2];
    #pragma unroll
    for (int c = 0; c < 2; ++c)
        qf[c] = *(const bf8*)&qb[(size_t)(n0w + lc) * 64 + c * 32 + g4 * 8];

    const f32x4 z4 = {0.f, 0.f, 0.f, 0.f};
    f32x4 od[4] = {z4, z4, z4, z4};
    float mrow[4] = {-1e30f, -1e30f, -1e30f, -1e30f};
    float lrow[4] = {0.f, 0.f, 0.f, 0.f};

    const int ntiles = bx + 1;
    for (int tt = 0; tt < ntiles; ++tt) {
        const int m0 = tt * 64;
        const int eB = 960 - n0 + m0;   // >= 0 always
        __syncthreads();
        // stage K tile
        #pragma unroll
        for (int ii = 0; ii < 2; ++ii) {
            int c = t + 256 * ii;
            int row = c >> 3, d8 = c & 7;
            *(uint4*)&k_s[row][d8 * 8] = *(const uint4*)&kb[(size_t)(m0 + row) * 64 + d8 * 8];
        }
        // stage Er tile rows [eB, eB+128), clamped (clamped rows are masked)
        #pragma unroll
        for (int ii = 0; ii < 4; ++ii) {
            int c = t + 256 * ii;
            int row = c >> 3, d8 = c & 7;
            int g = eB + row; g = (g > 1023) ? 1023 : g;
            *(uint4*)&e_s[row][d8 * 8] = *(const uint4*)&erg[(size_t)g * 64 + d8 * 8];
        }
        // stage V transposed: vt_s[d][m] (bf16 -> bf16)
        #pragma unroll
        for (int ii = 0; ii < 2; ++ii) {
            int c = t + 256 * ii;
            int m = c >> 3, d8 = c & 7;
            uint4 vv = *(const uint4*)&vb[(size_t)(m0 + m) * 64 + d8 * 8];
            const ushort* pp = (const ushort*)&vv;
            #pragma unroll
            for (int j = 0; j < 8; ++j) vt_s[d8 * 8 + j][m] = pp[j];
        }
        __syncthreads();

        if (m0 <= n0w + 15) {
            // content scores
            f32x4 sc[4] = {z4, z4, z4, z4};
            #pragma unroll
            for (int jt = 0; jt < 4; ++jt)
                #pragma unroll
                for (int c = 0; c < 2; ++c)
                    sc[jt] = __builtin_amdgcn_mfma_f32_16x16x32_bf16(
                        qf[c], *(const bf8*)&k_s[jt * 16 + lc][c * 32 + g4 * 8], sc[jt], 0, 0, 0);

            // rel tile R[16][80]
            f32x4 rc[5] = {z4, z4, z4, z4, z4};
            const int ew0 = 48 - 16 * w;
            #pragma unroll
            for (int jr = 0; jr < 5; ++jr)
                #pragma unroll
                for (int c = 0; c < 2; ++c)
                    rc[jr] = __builtin_amdgcn_mfma_f32_16x16x32_bf16(
                        qf[c], *(const bf8*)&e_s[ew0 + jr * 16 + lc][c * 32 + g4 * 8], rc[jr], 0, 0, 0);

            #pragma unroll
            for (int jr = 0; jr < 5; ++jr)
                #pragma unroll
                for (int i = 0; i < 4; ++i)
                    r_s[w][g4 * 4 + i][jr * 16 + lc] = f2bf(rc[jr][i]);
            asm volatile("s_waitcnt lgkmcnt(0)" ::: "memory");

            float a_[4];
            #pragma unroll
            for (int i = 0; i < 4; ++i) {
                const int row = g4 * 4 + i;
                const int n   = n0w + row;
                float sv[4];
                #pragma unroll
                for (int jt = 0; jt < 4; ++jt) {
                    int colR = jt * 16 + lc + 15 - row;     // in [0,78]
                    float rel = bf2f(r_s[w][row][colR]);
                    float s = (sc[jt][i] + rel) * 0.125f;
                    int m = m0 + jt * 16 + lc;
                    sv[jt] = (m <= n) ? s : -1e30f;
                }
                float tmax = fmaxf(fmaxf(sv[0], sv[1]), fmaxf(sv[2], sv[3]));
                #pragma unroll
                for (int off = 1; off < 16; off <<= 1)
                    tmax = fmaxf(tmax, __shfl_xor(tmax, off, 16));
                float mnew = fmaxf(mrow[i], tmax);
                float psum = 0.f;
                #pragma unroll
                for (int jt = 0; jt < 4; ++jt) {
                    float p = __expf(sv[jt] - mnew);
                    p_s[w][row][jt * 16 + lc] = f2bf(p);
                    psum += p;
                }
                #pragma unroll
                for (int off = 1; off < 16; off <<= 1)
                    psum += __shfl_xor(psum, off, 16);
                float alpha = __expf(mrow[i] - mnew);
                mrow[i] = mnew;
                lrow[i] = lrow[i] * alpha + psum;
                a_[i] = alpha;
            }

            #pragma unroll
            for (int dt = 0; dt < 4; ++dt)
                #pragma unroll
                for (int i = 0; i < 4; ++i)
                    od[dt][i] *= a_[i];

            asm volatile("s_waitcnt lgkmcnt(0)" ::: "memory");
            bf8 pf[2];
            #pragma unroll
            for (int c = 0; c < 2; ++c)
                pf[c] = *(const bf8*)&p_s[w][lc][c * 32 + g4 * 8];
            #pragma unroll
            for (int dt = 0; dt < 4; ++dt)
                #pragma unroll
                for (int c = 0; c < 2; ++c)
                    od[dt] = __builtin_amdgcn_mfma_f32_16x16x32_bf16(
                        pf[c], *(const bf8*)&vt_s[dt * 16 + lc][c * 32 + g4 * 8], od[dt], 0, 0, 0);
        }
    }

    // epilogue: attn out bf16 [b][n][h*64+d]
    #pragma unroll
    for (int i = 0; i < 4; ++i) {
        const int row = g4 * 4 + i;
        const int n   = n0w + row;
        const float inv = 1.f / lrow[i];
        #pragma unroll
        for (int dt = 0; dt < 4; ++dt)
            outp[((size_t)(b * 1024) + n) * 1024 + h * 64 + dt * 16 + lc] =
                f2bf(od[dt][i] * inv);
    }
}

// ---------------------------------------------------------------------------
extern "C" void kernel_launch(void* const* d_in, const int* in_sizes, int n_in,
                              void* d_out, int out_size, void* d_ws, size_t ws_size,
                              hipStream_t stream)
{
    const float* x     = (const float*)d_in[0];
    const float* Wqkv  = (const float*)d_in[1];
    const float* Wproj = (const float*)d_in[2];
    const float* bproj = (const float*)d_in[3];
    const float* Er    = (const float*)d_in[4];
    float* out = (float*)d_out;

    const size_t per = (size_t)BATCH * HEADS * SEQ * HDIM;   // 4,194,304
    ushort* xb     = (ushort*)d_ws;
    ushort* wqkvb  = xb + (size_t)4194304;
    ushort* wprojb = wqkvb + (size_t)3145728;
    ushort* erb    = wprojb + (size_t)1048576;
    ushort* qw     = erb + (size_t)65536;
    ushort* kw     = qw + per;
    ushort* vw     = kw + per;
    ushort* attnb  = vw + per;

    // fp32 -> bf16 conversions
    cvt_kernel<<<dim3(2048), 256, 0, stream>>>(x, xb);
    cvt_kernel<<<dim3(1536), 256, 0, stream>>>(Wqkv, wqkvb);
    cvt_kernel<<<dim3(512),  256, 0, stream>>>(Wproj, wprojb);
    cvt_kernel<<<dim3(32),   256, 0, stream>>>(Er, erb);

    // qkv GEMM: (4096 x 3072 x 1024) MFMA bf16
    gemm_qkv_mfma<<<dim3(F3 / 128, (BATCH * SEQ) / 128), 256, 0, stream>>>(
        xb, wqkvb, qw, kw, vw);

    // attention
    attn_mfma_kernel<<<dim3(SEQ / 64, HEADS, BATCH), 256, 0, stream>>>(
        qw, kw, vw, erb, attnb);

    // proj GEMM + bias: (4096 x 1024 x 1024) MFMA bf16, fp32 out
    gemm_proj_mfma<<<dim3(DIM_C / 128, (BATCH * SEQ) / 128), 256, 0, stream>>>(
        attnb, wprojb, bproj, out);
}